// Round 1
// baseline (976.961 us; speedup 1.0000x reference)
//
#include <hip/hip_runtime.h>
#include <hip/hip_fp16.h>

#define H 256
#define HETD 3
#define AH 128
#define BSEG 64
#define NB 128          // nodes per block in the fused kernel (4 waves x 32)
#define XPITCH 264      // f16 elements per LDS x-row (256 + 8 pad -> conflict-free)

typedef _Float16 half8 __attribute__((ext_vector_type(8)));
typedef _Float16 half4 __attribute__((ext_vector_type(4)));
typedef __attribute__((ext_vector_type(4))) float f32x4;

// ---------------------------------------------------------------------------
// Pack W1 [259][128] fp32 -> f16 MFMA B-fragments.
// Layout: frag index ((t*8 + nt)*64 + lane), 8 f16 per lane.
// B[k][n]: n = nt*16 + (lane&15), k = t*32 + (lane>>4)*8 + j, zero-pad k>=259.
// ---------------------------------------------------------------------------
__global__ void pack_w1_kernel(const float* __restrict__ W1,
                               unsigned short* __restrict__ W1p) {
    int idx = blockIdx.x * 256 + threadIdx.x;
    if (idx >= 9 * 8 * 64 * 8) return;
    int j    = idx & 7;
    int lane = (idx >> 3) & 63;
    int nt   = (idx >> 9) & 7;
    int t    = idx >> 12;
    int n = nt * 16 + (lane & 15);
    int k = t * 32 + ((lane >> 4) & 3) * 8 + j;
    float w = (k < (H + HETD)) ? W1[k * AH + n] : 0.f;
    __half hw = __float2half(w);
    W1p[idx] = __half_as_ushort(hw);
}

__device__ __forceinline__ _Float16 f2h(float f) { return (_Float16)f; }

// ---------------------------------------------------------------------------
// FUSED gate + segment-accumulate.  One block = 128 nodes (4 waves x 32).
// Phase 1 (gate): raw_i = tanh([x_i;het_i] @ W1 + b1) @ W2 + b2 ; p_i = exp(raw)
//   via 16x16x32 f16 MFMA (M=32/wave over 2 mtiles, N=128 over 8 ntiles,
//   K=288 over 9 ktiles).  The f16-converted x tile is ALSO stored to LDS,
//   so x is fetched from HBM exactly once.
// Phase 2 (accum): S[seg][c] += p_i * x_i[c] from the LDS tile.  batch is
//   sorted, so each lane run-accumulates in registers and flushes via global
//   atomics only at segment changes (lane covers 4 consecutive columns).
// ---------------------------------------------------------------------------
__global__ __launch_bounds__(256) void fused_gate_accum(
    const float* __restrict__ x, const float* __restrict__ het,
    const int* __restrict__ batch, const unsigned short* __restrict__ W1p,
    const float* __restrict__ b1, const float* __restrict__ W2,
    const float* __restrict__ b2, float* __restrict__ p,
    float* __restrict__ d, float* __restrict__ S, int n_nodes)
{
    __shared__ _Float16 sx[NB * XPITCH];   // 67.6 KB f16 x-tile
    __shared__ float sW2[AH];
    __shared__ float sb1[AH];
    __shared__ float sp[NB];
    __shared__ int   sbat[NB];
    __shared__ float sd[BSEG];

    int tid = threadIdx.x;
    long long base = (long long)blockIdx.x * NB;

    if (tid < AH) { sW2[tid] = W2[tid]; sb1[tid] = b1[tid]; }
    if (tid < BSEG) sd[tid] = 0.f;
    if (tid < NB) {
        sp[tid] = 0.f;  // tail nodes contribute 0 in phase 2
        long long nd = base + tid;
        sbat[tid] = batch[nd < n_nodes ? nd : (long long)(n_nodes - 1)];
    }
    __syncthreads();

    int lane = tid & 63;
    int wv   = tid >> 6;
    int row  = lane & 15;
    int quad = lane >> 4;
    long long wbase = base + (long long)wv * 32;

    if (wbase < n_nodes) {
        f32x4 acc[2][8] = {};
        int nodeA[2];
#pragma unroll
        for (int m = 0; m < 2; ++m) {
            long long nd = wbase + m * 16 + row;
            nodeA[m] = (int)(nd < n_nodes ? nd : (long long)(n_nodes - 1));
        }
        const uint4* W1p4 = (const uint4*)W1p;

        // K-tiles 0..7: the x part (k = 0..255).  Each lane's A-fragment is
        // 8 consecutive f16 of one row -> store straight to the LDS tile.
        for (int t = 0; t < 8; ++t) {
            half8 a[2];
#pragma unroll
            for (int m = 0; m < 2; ++m) {
                const float4* xr =
                    (const float4*)(x + (size_t)nodeA[m] * H + t * 32 + quad * 8);
                float4 lo = xr[0];
                float4 hi = xr[1];
                half8 av;
                av[0] = f2h(lo.x); av[1] = f2h(lo.y);
                av[2] = f2h(lo.z); av[3] = f2h(lo.w);
                av[4] = f2h(hi.x); av[5] = f2h(hi.y);
                av[6] = f2h(hi.z); av[7] = f2h(hi.w);
                a[m] = av;
                *(half8*)&sx[(wv * 32 + m * 16 + row) * XPITCH
                             + t * 32 + quad * 8] = av;
            }
#pragma unroll
            for (int nt = 0; nt < 8; ++nt) {
                union { uint4 u; half8 h; } cv;
                cv.u = W1p4[(t * 8 + nt) * 64 + lane];
#pragma unroll
                for (int m = 0; m < 2; ++m)
                    acc[m][nt] = __builtin_amdgcn_mfma_f32_16x16x32_f16(
                        a[m], cv.h, acc[m][nt], 0, 0, 0);
            }
        }
        // K-tile 8: het (k = 256..258) + zero pad
        {
            half8 a[2];
#pragma unroll
            for (int m = 0; m < 2; ++m) {
                half8 av = {0, 0, 0, 0, 0, 0, 0, 0};
                if (quad == 0) {
                    const float* hr = het + (size_t)nodeA[m] * HETD;
                    av[0] = f2h(hr[0]); av[1] = f2h(hr[1]); av[2] = f2h(hr[2]);
                }
                a[m] = av;
            }
#pragma unroll
            for (int nt = 0; nt < 8; ++nt) {
                union { uint4 u; half8 h; } cv;
                cv.u = W1p4[(8 * 8 + nt) * 64 + lane];
#pragma unroll
                for (int m = 0; m < 2; ++m)
                    acc[m][nt] = __builtin_amdgcn_mfma_f32_16x16x32_f16(
                        a[m], cv.h, acc[m][nt], 0, 0, 0);
            }
        }

        // Epilogue: tanh -> @W2 -> exp.  C/D layout: n = nt*16 + (lane&15),
        // node_local = wv*32 + m*16 + quad*4 + r.
        float b2v = b2[0];
#pragma unroll
        for (int m = 0; m < 2; ++m) {
#pragma unroll
            for (int r = 0; r < 4; ++r) {
                float partial = 0.f;
#pragma unroll
                for (int nt = 0; nt < 8; ++nt) {
                    int nn = nt * 16 + row;
                    float h = acc[m][nt][r] + sb1[nn];
                    // tanh(h) = 1 - 2/(e^{2h}+1); inf-safe at both ends
                    float e2 = __expf(2.f * h);
                    partial += (1.f - 2.f / (e2 + 1.f)) * sW2[nn];
                }
                partial += __shfl_xor(partial, 1);
                partial += __shfl_xor(partial, 2);
                partial += __shfl_xor(partial, 4);
                partial += __shfl_xor(partial, 8);
                int nl = wv * 32 + m * 16 + quad * 4 + r;
                long long node = base + nl;
                if (row == r && node < n_nodes) {
                    float pe = __expf(partial + b2v);
                    p[node] = pe;
                    sp[nl] = pe;
                    atomicAdd(&sd[sbat[nl]], pe);
                }
            }
        }
    }
    __syncthreads();

    if (tid < BSEG) {
        float v = sd[tid];
        if (v != 0.f) atomicAdd(&d[tid], v);
    }

    // Phase 2: S[seg] += p_i * x_i from LDS.  Wave wv handles nodes
    // wv, wv+4, ... (monotone -> run-accumulate works on sorted batch);
    // lane covers columns lane*4 .. lane*4+3 (coalesced atomics).
    {
        float a0 = 0.f, a1 = 0.f, a2 = 0.f, a3 = 0.f;
        int cur = -1;
        for (int i = wv; i < NB; i += 4) {
            if (base + i >= n_nodes) break;
            int sg = sbat[i];
            float pi = sp[i];
            if (sg != cur) {           // wave-uniform (same i per wave)
                if (cur >= 0) {
                    float* Sp = S + cur * H + lane * 4;
                    atomicAdd(Sp + 0, a0); atomicAdd(Sp + 1, a1);
                    atomicAdd(Sp + 2, a2); atomicAdd(Sp + 3, a3);
                }
                cur = sg; a0 = a1 = a2 = a3 = 0.f;
            }
            half4 xv = *(const half4*)&sx[i * XPITCH + lane * 4];
            a0 += pi * (float)xv[0];
            a1 += pi * (float)xv[1];
            a2 += pi * (float)xv[2];
            a3 += pi * (float)xv[3];
        }
        if (cur >= 0) {
            float* Sp = S + cur * H + lane * 4;
            atomicAdd(Sp + 0, a0); atomicAdd(Sp + 1, a1);
            atomicAdd(Sp + 2, a2); atomicAdd(Sp + 3, a3);
        }
    }
}

// ---------------------------------------------------------------------------
// attn_i = p_i / d[batch_i]
// ---------------------------------------------------------------------------
__global__ void attn_kernel(const float* __restrict__ p,
                            const int* __restrict__ batch,
                            const float* __restrict__ d,
                            float* __restrict__ attn, int n_nodes) {
    int i = blockIdx.x * 256 + threadIdx.x;
    if (i < n_nodes) attn[i] = p[i] / d[batch[i]];
}

// ---------------------------------------------------------------------------
// z[b] = (S[b]/d[b]) @ Wv + bv   (empty segment -> 0, matching segsum)
// ---------------------------------------------------------------------------
__global__ __launch_bounds__(256) void z_kernel(
    const float* __restrict__ S, const float* __restrict__ d,
    const float* __restrict__ Wv, const float* __restrict__ bv,
    float* __restrict__ z)
{
    __shared__ float sA[H];
    int b = blockIdx.x;
    int j = threadIdx.x;
    float dv = d[b];
    float inv = (dv != 0.f) ? 1.f / dv : 0.f;
    sA[j] = S[b * H + j] * inv;
    __syncthreads();
    float sum = (dv != 0.f) ? bv[j] : 0.f;
#pragma unroll 4
    for (int h = 0; h < H; ++h)
        sum += sA[h] * Wv[h * H + j];
    z[b * H + j] = sum;
}

extern "C" void kernel_launch(void* const* d_in, const int* in_sizes, int n_in,
                              void* d_out, int out_size, void* d_ws, size_t ws_size,
                              hipStream_t stream)
{
    const float* x   = (const float*)d_in[0];
    const float* het = (const float*)d_in[1];
    const int*   bat = (const int*)d_in[2];
    const float* W1  = (const float*)d_in[3];
    const float* b1  = (const float*)d_in[4];
    const float* W2  = (const float*)d_in[5];
    const float* b2  = (const float*)d_in[6];
    const float* Wv  = (const float*)d_in[7];
    const float* bv  = (const float*)d_in[8];
    int n = in_sizes[0] / H;  // 500000

    // ws layout: d[64] | S[64*256] | p[n] | W1p (f16 frags, 36864 shorts)
    float* wsf = (float*)d_ws;
    float* d_d = wsf;
    float* d_S = wsf + BSEG;
    float* d_p = wsf + BSEG + BSEG * H;
    unsigned short* d_W1p = (unsigned short*)(wsf + BSEG + BSEG * H + n);

    hipMemsetAsync(d_d, 0, (BSEG + BSEG * H) * sizeof(float), stream);
    pack_w1_kernel<<<(9 * 8 * 64 * 8 + 255) / 256, 256, 0, stream>>>(W1, d_W1p);

    int blocks = (n + NB - 1) / NB;
    fused_gate_accum<<<blocks, 256, 0, stream>>>(x, het, bat, d_W1p, b1, W2, b2,
                                                 d_p, d_d, d_S, n);
    attn_kernel<<<(n + 255) / 256, 256, 0, stream>>>(d_p, bat, d_d,
                                                     (float*)d_out + BSEG * H, n);
    z_kernel<<<BSEG, 256, 0, stream>>>(d_S, d_d, Wv, bv, (float*)d_out);
}